// Round 7
// baseline (177.419 us; speedup 1.0000x reference)
//
#include <hip/hip_runtime.h>

// irreps: x1 = 128x0e + 128x1o (512), x2 = 1x0e + 1x1o (4), w = 5*128 (640)
// out = 128x0e + 128x1o (512). All fp32. Memory-bound streaming op.
//
// Per edge z, channel u:
//   s = x1[z,u]; v = x1[z,128+3u .. +3); a = x2[z,0]; b = x2[z,1..4)
//   out[z,u]        = s*a*w0[u] + (1/sqrt3)*(v.b)*w3[u]
//   out[z,128+3u+k] = (1/sqrt3)*s*w1[u]*b[k] + (1/sqrt3)*a*w2[u]*v[k]
//                   + (1/sqrt6)*w4[u]*(v x b)[k]
//
// R7: PERSISTENT GRID-STRIDE, simple body. History:
//   R4 (one-shot, direct loads): 156.6us, 2.9 TB/s HBM-side.
//   R5 (forced A/B reg pipeline): spilled (LDS 20KB), 39% occ, regressed.
//   R6 (LDS transpose, ideal traffic): BW flat -> access pattern not the wall.
// All one-shot variants sit at ~2.9-3.0 TB/s while loop-structured kernels
// (fillBuffer 6.9 TB/s, m13 copy 6.3 TB/s) go 2x+ faster on this chip.
// Theory: 65K single-trip waves each start with an empty vmem queue and
// drain it at exit; SPI turnover + ramp dominates. Fix: 2048 blocks (8/CU),
// each block owns 64 contiguous edges, each thread loops 8 iterations.
// NO forced pipelining, NO sched_barrier — compiler schedules the loop
// (lesson R5 / common-mistake #5).

typedef float f32x4 __attribute__((ext_vector_type(4)));

#define EDGES_PER_BLOCK 64
#define EDGES_PER_ITER  8      // 256 threads / 32 threads-per-edge

__global__ __launch_bounds__(256) void tp_uvu_kernel(
    const float* __restrict__ x1,
    const float* __restrict__ x2,
    const float* __restrict__ w,
    float* __restrict__ out,
    int n_edges)
{
    const int g    = threadIdx.x & 31;           // channel group: 4g..4g+3
    const int eoff = threadIdx.x >> 5;           // 0..7
    const int base = blockIdx.x * EDGES_PER_BLOCK;

    constexpr float inv_sqrt3 = 0.57735026918962576f;
    constexpr float inv_sqrt6 = 0.40824829046386302f;

    for (int i = 0; i < EDGES_PER_BLOCK / EDGES_PER_ITER; ++i) {
        const int z = base + i * EDGES_PER_ITER + eoff;
        if (z >= n_edges) break;

        const float* x1row  = x1  + (size_t)z * 512;
        const float* wrow   = w   + (size_t)z * 640;
        float*       outrow = out + (size_t)z * 512;

        const f32x4 x2v = *reinterpret_cast<const f32x4*>(x2 + (size_t)z * 4);
        const f32x4 s4  = *reinterpret_cast<const f32x4*>(x1row + 4 * g);
        const f32x4 va  = *reinterpret_cast<const f32x4*>(x1row + 128 + 12 * g);
        const f32x4 vb  = *reinterpret_cast<const f32x4*>(x1row + 128 + 12 * g + 4);
        const f32x4 vc  = *reinterpret_cast<const f32x4*>(x1row + 128 + 12 * g + 8);
        const f32x4 w0  = *reinterpret_cast<const f32x4*>(wrow +   0 + 4 * g);
        const f32x4 w1  = *reinterpret_cast<const f32x4*>(wrow + 128 + 4 * g);
        const f32x4 w2  = *reinterpret_cast<const f32x4*>(wrow + 256 + 4 * g);
        const f32x4 w3  = *reinterpret_cast<const f32x4*>(wrow + 384 + 4 * g);
        const f32x4 w4  = *reinterpret_cast<const f32x4*>(wrow + 512 + 4 * g);

        const float a  = x2v.x;
        const float bx = x2v.y, by = x2v.z, bz = x2v.w;

        const float s[4]   = {s4.x, s4.y, s4.z, s4.w};
        const float vv[12] = {va.x, va.y, va.z, va.w,
                              vb.x, vb.y, vb.z, vb.w,
                              vc.x, vc.y, vc.z, vc.w};
        const float W0[4]  = {w0.x, w0.y, w0.z, w0.w};
        const float W1[4]  = {w1.x, w1.y, w1.z, w1.w};
        const float W2[4]  = {w2.x, w2.y, w2.z, w2.w};
        const float W3[4]  = {w3.x, w3.y, w3.z, w3.w};
        const float W4[4]  = {w4.x, w4.y, w4.z, w4.w};

        float os[4];
        float ov[12];
#pragma unroll
        for (int c = 0; c < 4; ++c) {
            const float vx = vv[3 * c + 0];
            const float vy = vv[3 * c + 1];
            const float vz = vv[3 * c + 2];
            const float dot = vx * bx + vy * by + vz * bz;
            os[c] = s[c] * a * W0[c] + inv_sqrt3 * dot * W3[c];

            const float cx = vy * bz - vz * by;   // v x b
            const float cy = vz * bx - vx * bz;
            const float cz = vx * by - vy * bx;

            const float t1 = inv_sqrt3 * s[c] * W1[c];
            const float t2 = inv_sqrt3 * a   * W2[c];
            const float t4 = inv_sqrt6 * W4[c];
            ov[3 * c + 0] = t1 * bx + t2 * vx + t4 * cx;
            ov[3 * c + 1] = t1 * by + t2 * vy + t4 * cy;
            ov[3 * c + 2] = t1 * bz + t2 * vz + t4 * cz;
        }

        f32x4 o0 = {os[0], os[1], os[2],  os[3]};
        f32x4 o1 = {ov[0], ov[1], ov[2],  ov[3]};
        f32x4 o2 = {ov[4], ov[5], ov[6],  ov[7]};
        f32x4 o3 = {ov[8], ov[9], ov[10], ov[11]};
        *reinterpret_cast<f32x4*>(outrow + 4 * g)            = o0;
        *reinterpret_cast<f32x4*>(outrow + 128 + 12 * g)     = o1;
        *reinterpret_cast<f32x4*>(outrow + 128 + 12 * g + 4) = o2;
        *reinterpret_cast<f32x4*>(outrow + 128 + 12 * g + 8) = o3;
    }
}

extern "C" void kernel_launch(void* const* d_in, const int* in_sizes, int n_in,
                              void* d_out, int out_size, void* d_ws, size_t ws_size,
                              hipStream_t stream) {
    const float* x1 = (const float*)d_in[0];
    const float* x2 = (const float*)d_in[1];
    const float* w  = (const float*)d_in[2];
    float* out = (float*)d_out;

    const int n_edges = in_sizes[0] / 512;
    const int grid = (n_edges + EDGES_PER_BLOCK - 1) / EDGES_PER_BLOCK;  // 2048

    tp_uvu_kernel<<<grid, 256, 0, stream>>>(x1, x2, w, out, n_edges);
}

// Round 8
// 153.767 us; speedup vs baseline: 1.1538x; 1.1538x over previous
//
#include <hip/hip_runtime.h>

// irreps: x1 = 128x0e + 128x1o (512), x2 = 1x0e + 1x1o (4), w = 5*128 (640)
// out = 128x0e + 128x1o (512). All fp32. Memory-bound streaming op.
//
// Per edge z, channel u:
//   s = x1[z,u]; v = x1[z,128+3u .. +3); a = x2[z,0]; b = x2[z,1..4)
//   out[z,u]        = s*a*w0[u] + (1/sqrt3)*(v.b)*w3[u]
//   out[z,128+3u+k] = (1/sqrt3)*s*w1[u]*b[k] + (1/sqrt3)*a*w2[u]*v[k]
//                   + (1/sqrt6)*w4[u]*(v x b)[k]
//
// R8 = R4 (best, 156.6us) + output-side LDS transpose (from R6, proven
// traffic-neutral) + NON-TEMPORAL stores. Rationale: request-side rate is
// already 89% of the copy ceiling; the only remaining fabric work we can
// REMOVE is the output's L2/L3 write-allocate + eviction (262 MB), which
// also evicts input lines (FETCH shows ~50% L3 input retention). nt is only
// safe on full-line contiguous stores -> transpose vector outputs in LDS
// first (R3's nt on 48B-strided stores ballooned WRITE to 326 MB).
// Wave-local LDS buffers, 32-lane lockstep, no __syncthreads (validated R6).

typedef float f32x4 __attribute__((ext_vector_type(4)));

__global__ __launch_bounds__(256) void tp_uvu_kernel(
    const float* __restrict__ x1,
    const float* __restrict__ x2,
    const float* __restrict__ w,
    float* __restrict__ out,
    int n_edges)
{
    __shared__ __align__(16) float lds[8][384];  // per-32-lane-group buffer

    const int tid = blockIdx.x * blockDim.x + threadIdx.x;
    const int z   = tid >> 5;            // edge index (32 threads per edge)
    const int g   = tid & 31;            // channel group: channels 4g..4g+3
    const int grp = threadIdx.x >> 5;    // LDS buffer index (0..7)
    if (z >= n_edges) return;

    constexpr float inv_sqrt3 = 0.57735026918962576f;
    constexpr float inv_sqrt6 = 0.40824829046386302f;

    const float* x1row  = x1  + (size_t)z * 512;
    const float* wrow   = w   + (size_t)z * 640;
    float*       outrow = out + (size_t)z * 512;
    float*       buf    = lds[grp];

    // ---- load phase: all 10 loads issued before any consumption ----
    const f32x4 x2v = *reinterpret_cast<const f32x4*>(x2 + (size_t)z * 4);
    const f32x4 s4  = *reinterpret_cast<const f32x4*>(x1row + 4 * g);
    const f32x4 va  = *reinterpret_cast<const f32x4*>(x1row + 128 + 12 * g);
    const f32x4 vb  = *reinterpret_cast<const f32x4*>(x1row + 128 + 12 * g + 4);
    const f32x4 vc  = *reinterpret_cast<const f32x4*>(x1row + 128 + 12 * g + 8);
    const f32x4 w0  = *reinterpret_cast<const f32x4*>(wrow +   0 + 4 * g);
    const f32x4 w1  = *reinterpret_cast<const f32x4*>(wrow + 128 + 4 * g);
    const f32x4 w2  = *reinterpret_cast<const f32x4*>(wrow + 256 + 4 * g);
    const f32x4 w3  = *reinterpret_cast<const f32x4*>(wrow + 384 + 4 * g);
    const f32x4 w4  = *reinterpret_cast<const f32x4*>(wrow + 512 + 4 * g);

    __builtin_amdgcn_sched_barrier(0);   // pin: loads issue before compute

    // ---- compute ----
    const float a  = x2v.x;
    const float bx = x2v.y, by = x2v.z, bz = x2v.w;

    const float s[4]   = {s4.x, s4.y, s4.z, s4.w};
    const float vv[12] = {va.x, va.y, va.z, va.w,
                          vb.x, vb.y, vb.z, vb.w,
                          vc.x, vc.y, vc.z, vc.w};
    const float W0[4]  = {w0.x, w0.y, w0.z, w0.w};
    const float W1[4]  = {w1.x, w1.y, w1.z, w1.w};
    const float W2[4]  = {w2.x, w2.y, w2.z, w2.w};
    const float W3[4]  = {w3.x, w3.y, w3.z, w3.w};
    const float W4[4]  = {w4.x, w4.y, w4.z, w4.w};

    float os[4];
    float ov[12];
#pragma unroll
    for (int c = 0; c < 4; ++c) {
        const float vx = vv[3 * c + 0];
        const float vy = vv[3 * c + 1];
        const float vz = vv[3 * c + 2];
        const float dot = vx * bx + vy * by + vz * bz;
        os[c] = s[c] * a * W0[c] + inv_sqrt3 * dot * W3[c];

        const float cx = vy * bz - vz * by;   // v x b
        const float cy = vz * bx - vx * bz;
        const float cz = vx * by - vy * bx;

        const float t1 = inv_sqrt3 * s[c] * W1[c];
        const float t2 = inv_sqrt3 * a   * W2[c];
        const float t4 = inv_sqrt6 * W4[c];
        ov[3 * c + 0] = t1 * bx + t2 * vx + t4 * cx;
        ov[3 * c + 1] = t1 * by + t2 * vy + t4 * cy;
        ov[3 * c + 2] = t1 * bz + t2 * vz + t4 * cz;
    }

    // scalar output: contiguous across lanes -> nt store direct
    f32x4 o0 = {os[0], os[1], os[2], os[3]};
    __builtin_nontemporal_store(o0, reinterpret_cast<f32x4*>(outrow + 4 * g));

    // ---- output LDS transpose: strided ds_write, contiguous read-back ----
    f32x4 o1 = {ov[0], ov[1], ov[2],  ov[3]};
    f32x4 o2 = {ov[4], ov[5], ov[6],  ov[7]};
    f32x4 o3 = {ov[8], ov[9], ov[10], ov[11]};
    *reinterpret_cast<f32x4*>(buf + 12 * g)     = o1;
    *reinterpret_cast<f32x4*>(buf + 12 * g + 4) = o2;
    *reinterpret_cast<f32x4*>(buf + 12 * g + 8) = o3;
    const f32x4 r0 = *reinterpret_cast<const f32x4*>(buf + 4 * g);
    const f32x4 r1 = *reinterpret_cast<const f32x4*>(buf + 4 * (g + 32));
    const f32x4 r2 = *reinterpret_cast<const f32x4*>(buf + 4 * (g + 64));
    __builtin_nontemporal_store(r0, reinterpret_cast<f32x4*>(outrow + 128 + 4 * g));
    __builtin_nontemporal_store(r1, reinterpret_cast<f32x4*>(outrow + 128 + 4 * (g + 32)));
    __builtin_nontemporal_store(r2, reinterpret_cast<f32x4*>(outrow + 128 + 4 * (g + 64)));
}

extern "C" void kernel_launch(void* const* d_in, const int* in_sizes, int n_in,
                              void* d_out, int out_size, void* d_ws, size_t ws_size,
                              hipStream_t stream) {
    const float* x1 = (const float*)d_in[0];
    const float* x2 = (const float*)d_in[1];
    const float* w  = (const float*)d_in[2];
    float* out = (float*)d_out;

    const int n_edges = in_sizes[0] / 512;
    const long long total_threads = (long long)n_edges * 32;
    const int block = 256;
    const int grid = (int)((total_threads + block - 1) / block);

    tp_uvu_kernel<<<grid, block, 0, stream>>>(x1, x2, w, out, n_edges);
}